// Round 10
// baseline (315.243 us; speedup 1.0000x reference)
//
#include <hip/hip_runtime.h>
#include <hip/hip_bf16.h>

typedef __attribute__((ext_vector_type(8))) short bf16x8;
typedef __attribute__((ext_vector_type(4))) float f32x4;

#define LOG2E 1.4426950408889634f

__device__ __forceinline__ ushort f2bf(float f) {
    return __builtin_bit_cast(ushort, __float2bfloat16(f));
}
__device__ __forceinline__ float bf2f(short u) {
    return __uint_as_float(((unsigned)(ushort)u) << 16);
}

// ---------------- kernel 1: per-half-row partial (Sum p*x, Sum p) ----------------
// Lean: VGPR target <=64 so 8 waves/SIMD (32 waves/CU) fit. W2 fragments in LDS,
// PV reuses bf16 A-frags, no manual prefetch (TLP hides latency).
__global__ __launch_bounds__(256, 8)
void attn_part(const float* __restrict__ full,
               const float* __restrict__ last,
               const float* __restrict__ W1w, const float* __restrict__ W1b,
               const float* __restrict__ W2w, const float* __restrict__ W2b,
               const float* __restrict__ Vw,  const float* __restrict__ Vb,
               float* __restrict__ accws, float* __restrict__ lws, int T)
{
    // W2 bf16 fragments pre-packed in per-lane MFMA layout:
    // fragment f = (ot*2+kc)*64 + ln holds W2[ot*16+(ln&15)][kc*32+(ln>>4)*8 + 0..7]
    __shared__ ushort w2f[512][8];      // 8 KB, lane-linear ds_read_b128 (stride 16B)
    __shared__ float qpart[4][64];
    __shared__ float qt[64];
    __shared__ float vsh[64];
    __shared__ float accbuf[4][64];
    __shared__ float lbuf[4];

    const int b    = blockIdx.x >> 1;   // batch row
    const int half = blockIdx.x & 1;    // which T-half
    const int tid  = threadIdx.x;
    const int lane = tid & 63;
    const int wv   = tid >> 6;          // wave 0..3
    const int col  = lane & 15;
    const int grp  = lane >> 4;
    const int koff = grp * 8;

    // ---------------- stage 0: q~ partials, W2 frag pack, V ----------------
    {
        const float4* lr = reinterpret_cast<const float4*>(last + (size_t)b * 64 + wv * 16);
        const float4* wr = reinterpret_cast<const float4*>(W1w + (size_t)lane * 64 + wv * 16);
        float s = 0.f;
        #pragma unroll
        for (int j = 0; j < 4; ++j) {
            float4 a = lr[j], w = wr[j];
            s = fmaf(a.x, w.x, s); s = fmaf(a.y, w.y, s);
            s = fmaf(a.z, w.z, s); s = fmaf(a.w, w.w, s);
        }
        qpart[wv][lane] = s;

        #pragma unroll
        for (int ff = 0; ff < 2; ++ff) {
            int f  = tid + ff * 256;
            int ot = f >> 7, kc = (f >> 6) & 1, ln = f & 63;
            const float* wp = W2w + (size_t)(ot * 16 + (ln & 15)) * 64 + kc * 32 + (ln >> 4) * 8;
            float4 x0 = *reinterpret_cast<const float4*>(wp);
            float4 x1 = *reinterpret_cast<const float4*>(wp + 4);
            ushort* dst = w2f[f];
            dst[0]=f2bf(x0.x); dst[1]=f2bf(x0.y); dst[2]=f2bf(x0.z); dst[3]=f2bf(x0.w);
            dst[4]=f2bf(x1.x); dst[5]=f2bf(x1.y); dst[6]=f2bf(x1.z); dst[7]=f2bf(x1.w);
        }
        if (tid < 64) vsh[tid] = Vw[tid];
    }
    __syncthreads();
    if (tid < 64)
        qt[tid] = W1b[tid] + W2b[tid] + qpart[0][tid] + qpart[1][tid]
                + qpart[2][tid] + qpart[3][tid];
    __syncthreads();

    // per-col folded constants
    float q2[4], vm2[4], sv = 0.f;
    #pragma unroll
    for (int ot = 0; ot < 4; ++ot) {
        float v = vsh[ot * 16 + col];
        vm2[ot] = -2.f * v;
        sv += v;
        q2[ot] = qt[ot * 16 + col] * (2.f * LOG2E);
    }
    const float vbl = Vb[0] * LOG2E;

    const int ntile = T / (2 * 4 * 16); // tiles per wave (T=2048 -> 16)
    // waves interleave tiles of the block's contiguous 256KB half-row stream
    const float* xbase = full + ((size_t)b * T + (size_t)half * (T / 2)
                                 + (size_t)wv * 16 + col) * 64 + koff;
    const ushort* wfbase = &w2f[0][0] + lane * 8;

    float acc16[16];
    #pragma unroll
    for (int i = 0; i < 16; ++i) acc16[i] = 0.f;
    float l = 0.f;

    for (int it = 0; it < ntile; ++it) {
        const float* xr = xbase + (size_t)it * 4096;
        f32x4 a00 = *reinterpret_cast<const f32x4*>(xr);
        f32x4 a01 = *reinterpret_cast<const f32x4*>(xr + 4);
        f32x4 a10 = *reinterpret_cast<const f32x4*>(xr + 32);
        f32x4 a11 = *reinterpret_cast<const f32x4*>(xr + 36);

        // convert once; f32 regs die here (PV reuses the bf16 frags)
        bf16x8 af0, af1;
        af0[0]=f2bf(a00[0]); af0[1]=f2bf(a00[1]); af0[2]=f2bf(a00[2]); af0[3]=f2bf(a00[3]);
        af0[4]=f2bf(a01[0]); af0[5]=f2bf(a01[1]); af0[6]=f2bf(a01[2]); af0[7]=f2bf(a01[3]);
        af1[0]=f2bf(a10[0]); af1[1]=f2bf(a10[1]); af1[2]=f2bf(a10[2]); af1[3]=f2bf(a10[3]);
        af1[4]=f2bf(a11[0]); af1[5]=f2bf(a11[1]); af1[6]=f2bf(a11[2]); af1[7]=f2bf(a11[3]);

        // hv[r] = sum_o V[o]*tanh(q_o + k[t,o]) (pre-reduction over 16 cols)
        float hv[4] = {sv, sv, sv, sv};
        #pragma unroll
        for (int ot = 0; ot < 4; ++ot) {
            bf16x8 b0 = *reinterpret_cast<const bf16x8*>(wfbase + (ot * 2 + 0) * 512);
            bf16x8 b1 = *reinterpret_cast<const bf16x8*>(wfbase + (ot * 2 + 1) * 512);
            f32x4 dd = {0.f, 0.f, 0.f, 0.f};
            dd = __builtin_amdgcn_mfma_f32_16x16x32_bf16(af0, b0, dd, 0, 0, 0);
            dd = __builtin_amdgcn_mfma_f32_16x16x32_bf16(af1, b1, dd, 0, 0, 0);
            #pragma unroll
            for (int r = 0; r < 4; ++r) {
                // tanh(x) = 1 - 2/(exp2(2x*log2e)+1); the "+1*v" is folded into sv
                float e  = exp2f(fmaf(dd[r], 2.f * LOG2E, q2[ot]));
                float rc = __builtin_amdgcn_rcpf(e + 1.f);
                hv[r] = fmaf(vm2[ot], rc, hv[r]);
            }
        }

        #pragma unroll
        for (int msk = 1; msk <= 8; msk <<= 1)
            #pragma unroll
            for (int r = 0; r < 4; ++r)
                hv[r] += __shfl_xor(hv[r], msk);

        // p = exp(score), fixed m=0 (scores bounded ~|Sigma|V||+|Vb| < 10)
        float p4[4];
        #pragma unroll
        for (int r = 0; r < 4; ++r)
            p4[r] = exp2f(fmaf(hv[r], LOG2E, vbl));

        l += (p4[0] + p4[1]) + (p4[2] + p4[3]);

        // p for local row = col: from lane group (col>>2), reg (col&3)
        int srcl = (col >> 2) * 16;
        float c0 = __shfl(p4[0], srcl);
        float c1 = __shfl(p4[1], srcl);
        float c2 = __shfl(p4[2], srcl);
        float c3 = __shfl(p4[3], srcl);
        float pa   = (col & 1) ? c1 : c0;
        float pb   = (col & 1) ? c3 : c2;
        float pcol = (col & 2) ? pb : pa;

        // PV from the bf16 frags; lane owns d = {koff+j, 32+koff+j, +4 variants}
        #pragma unroll
        for (int j = 0; j < 4; ++j) {
            acc16[j]      = fmaf(pcol, bf2f(af0[j]),     acc16[j]);
            acc16[4 + j]  = fmaf(pcol, bf2f(af0[4 + j]), acc16[4 + j]);
            acc16[8 + j]  = fmaf(pcol, bf2f(af1[j]),     acc16[8 + j]);
            acc16[12 + j] = fmaf(pcol, bf2f(af1[4 + j]), acc16[12 + j]);
        }
    }

    // ---------------- end reductions ----------------
    #pragma unroll
    for (int msk = 1; msk <= 8; msk <<= 1)
        #pragma unroll
        for (int i = 0; i < 16; ++i)
            acc16[i] += __shfl_xor(acc16[i], msk);

    l += __shfl_xor(l, 16);
    l += __shfl_xor(l, 32);

    if (col == 0) {
        #pragma unroll
        for (int j = 0; j < 8; ++j) {
            accbuf[wv][grp * 8 + j]      = acc16[j];
            accbuf[wv][32 + grp * 8 + j] = acc16[8 + j];
        }
    }
    if (lane == 0) lbuf[wv] = l;
    __syncthreads();

    if (tid < 64) {
        float a = (accbuf[0][tid] + accbuf[1][tid])
                + (accbuf[2][tid] + accbuf[3][tid]);
        accws[(size_t)blockIdx.x * 64 + tid] = a;
        if (tid == 0)
            lws[blockIdx.x] = (lbuf[0] + lbuf[1]) + (lbuf[2] + lbuf[3]);
    }
}

// ---------------- kernel 2: combine halves ----------------
__global__ __launch_bounds__(64)
void attn_combine(const float* __restrict__ accws, const float* __restrict__ lws,
                  float* __restrict__ out)
{
    const int b = blockIdx.x, d = threadIdx.x;
    float a = accws[(size_t)(2 * b) * 64 + d] + accws[(size_t)(2 * b + 1) * 64 + d];
    float L = lws[2 * b] + lws[2 * b + 1];
    out[(size_t)b * 64 + d] = a / L;
}

extern "C" void kernel_launch(void* const* d_in, const int* in_sizes, int n_in,
                              void* d_out, int out_size, void* d_ws, size_t ws_size,
                              hipStream_t stream) {
    const float* full = (const float*)d_in[0];
    const float* last = (const float*)d_in[1];
    const float* W1w  = (const float*)d_in[2];
    const float* W1b  = (const float*)d_in[3];
    const float* W2w  = (const float*)d_in[4];
    const float* W2b  = (const float*)d_in[5];
    const float* Vw   = (const float*)d_in[6];
    const float* Vb   = (const float*)d_in[7];
    float* out = (float*)d_out;

    const int Bn = in_sizes[1] / 64;              // 1024
    const int T  = in_sizes[0] / in_sizes[1];     // 2048

    float* accws = (float*)d_ws;                  // [2*Bn][64]
    float* lws   = accws + (size_t)2 * Bn * 64;   // [2*Bn]

    attn_part<<<2 * Bn, 256, 0, stream>>>(full, last, W1w, W1b, W2w, W2b, Vw, Vb,
                                          accws, lws, T);
    attn_combine<<<Bn, 64, 0, stream>>>(accws, lws, out);
}

// Round 11
// 116.606 us; speedup vs baseline: 2.7035x; 2.7035x over previous
//
#include <hip/hip_runtime.h>
#include <hip/hip_bf16.h>

typedef __attribute__((ext_vector_type(8))) short bf16x8;
typedef __attribute__((ext_vector_type(4))) float f32x4;

#define LOG2E 1.4426950408889634f

__device__ __forceinline__ ushort f2bf(float f) {
    // RNE f32->bf16 via header cast; compiler fuses pairs into v_cvt_pk_bf16_f32
    return __builtin_bit_cast(ushort, __float2bfloat16(f));
}

struct TileRegs { f32x4 a00, a01, a10, a11; };

__device__ __forceinline__ void load_tile(TileRegs& t, const float* xr) {
    t.a00 = *reinterpret_cast<const f32x4*>(xr);
    t.a01 = *reinterpret_cast<const f32x4*>(xr + 4);
    t.a10 = *reinterpret_cast<const f32x4*>(xr + 32);
    t.a11 = *reinterpret_cast<const f32x4*>(xr + 36);
}

// ---------------- kernel 1: per-quarter-row partial (Sum p*x, Sum p) ----------------
__global__ __launch_bounds__(256, 4)
void attn_part(const float* __restrict__ full,
               const float* __restrict__ last,
               const float* __restrict__ W1w, const float* __restrict__ W1b,
               const float* __restrict__ W2w, const float* __restrict__ W2b,
               const float* __restrict__ Vw,  const float* __restrict__ Vb,
               float* __restrict__ accws, float* __restrict__ lws, int T)
{
    __shared__ ushort w2bf[64][64];     // bf16 bits of W2 [o][d]
    __shared__ float qpart[4][64];
    __shared__ float qt[64];            // q~ = W1b + W2b + last @ W1^T
    __shared__ float vsh[64];
    __shared__ float accbuf[4][64];
    __shared__ float lbuf[4];

    const int b    = blockIdx.x >> 2;   // batch row
    const int qtr  = blockIdx.x & 3;    // which T-quarter
    const int tid  = threadIdx.x;
    const int lane = tid & 63;
    const int wv   = tid >> 6;          // wave 0..3
    const int col  = lane & 15;         // A-row (t) index / B,D col (o) index
    const int grp  = lane >> 4;         // k-group
    const int koff = grp * 8;

    // ---------------- stage 0: q~, W2->bf16, V ----------------
    {
        int o = tid & 63, pg = tid >> 6;
        const float4* lr = reinterpret_cast<const float4*>(last + (size_t)b * 64 + pg * 16);
        const float4* wr = reinterpret_cast<const float4*>(W1w + (size_t)o * 64 + pg * 16);
        float s = 0.f;
        #pragma unroll
        for (int j = 0; j < 4; ++j) {
            float4 a = lr[j], w = wr[j];
            s = fmaf(a.x, w.x, s); s = fmaf(a.y, w.y, s);
            s = fmaf(a.z, w.z, s); s = fmaf(a.w, w.w, s);
        }
        qpart[pg][o] = s;

        int base = tid * 16;
        #pragma unroll
        for (int j = 0; j < 16; j += 4) {
            float4 w4 = *reinterpret_cast<const float4*>(W2w + base + j);
            ushort* dst = &w2bf[0][0] + base + j;
            dst[0] = f2bf(w4.x); dst[1] = f2bf(w4.y);
            dst[2] = f2bf(w4.z); dst[3] = f2bf(w4.w);
        }
        if (tid < 64) vsh[tid] = Vw[tid];
    }
    __syncthreads();
    if (tid < 64)
        qt[tid] = W1b[tid] + W2b[tid] + qpart[0][tid] + qpart[1][tid]
                + qpart[2][tid] + qpart[3][tid];
    __syncthreads();

    // B fragments: B[k=d, c=o] = W2^T  -> lane holds W2[ot*16+col][kc*32+koff .. +7]
    bf16x8 bfr[4][2];
    #pragma unroll
    for (int ot = 0; ot < 4; ++ot)
        #pragma unroll
        for (int kc = 0; kc < 2; ++kc)
            bfr[ot][kc] = *reinterpret_cast<const bf16x8*>(
                              &w2bf[ot * 16 + col][kc * 32 + koff]);

    // per-col folded constants
    float q2[4], vm2[4], sv = 0.f;
    #pragma unroll
    for (int ot = 0; ot < 4; ++ot) {
        float v = vsh[ot * 16 + col];
        vm2[ot] = -2.f * v;
        sv += v;
        q2[ot] = qt[ot * 16 + col] * (2.f * LOG2E);
    }
    const float vbl = Vb[0] * LOG2E;

    const int ntile = T / (4 * 4 * 16); // tiles per wave (T=2048 -> 8)
    // waves interleave tiles of the block's contiguous 128KB quarter-row stream
    // (wave wv owns tiles wv, wv+4, ...); tile k at xbase + k*4096 floats
    const float* xbase = full + ((size_t)b * T + (size_t)qtr * (T / 4)
                                 + (size_t)wv * 16 + col) * 64 + koff;

    float acc16[16];
    #pragma unroll
    for (int i = 0; i < 16; ++i) acc16[i] = 0.f;
    float l = 0.f;

    const int lastIt = ntile - 1;

    TileRegs A, B;
    load_tile(A, xbase);

    // compute one 16-row tile held in regs `t`
    auto compute = [&](const TileRegs& t) {
        bf16x8 af0, af1;
        af0[0]=f2bf(t.a00[0]); af0[1]=f2bf(t.a00[1]); af0[2]=f2bf(t.a00[2]); af0[3]=f2bf(t.a00[3]);
        af0[4]=f2bf(t.a01[0]); af0[5]=f2bf(t.a01[1]); af0[6]=f2bf(t.a01[2]); af0[7]=f2bf(t.a01[3]);
        af1[0]=f2bf(t.a10[0]); af1[1]=f2bf(t.a10[1]); af1[2]=f2bf(t.a10[2]); af1[3]=f2bf(t.a10[3]);
        af1[4]=f2bf(t.a11[0]); af1[5]=f2bf(t.a11[1]); af1[6]=f2bf(t.a11[2]); af1[7]=f2bf(t.a11[3]);

        // hv[r] = sum_o V[o]*tanh(q_o + k[t,o]),  t-row = grp*4 + r (pre-reduction)
        float hv[4] = {sv, sv, sv, sv};
        #pragma unroll
        for (int ot = 0; ot < 4; ++ot) {
            f32x4 dd = {0.f, 0.f, 0.f, 0.f};
            dd = __builtin_amdgcn_mfma_f32_16x16x32_bf16(af0, bfr[ot][0], dd, 0, 0, 0);
            dd = __builtin_amdgcn_mfma_f32_16x16x32_bf16(af1, bfr[ot][1], dd, 0, 0, 0);
            #pragma unroll
            for (int r = 0; r < 4; ++r) {
                // tanh(x) = 1 - 2/(exp2(2x*log2e)+1); the "+1*v" is folded into sv
                float e  = exp2f(fmaf(dd[r], 2.f * LOG2E, q2[ot]));
                float rc = __builtin_amdgcn_rcpf(e + 1.f);
                hv[r] = fmaf(vm2[ot], rc, hv[r]);
            }
        }

        // reduce over the 16 o-cols (lane bits 0..3)
        #pragma unroll
        for (int msk = 1; msk <= 8; msk <<= 1)
            #pragma unroll
            for (int r = 0; r < 4; ++r)
                hv[r] += __shfl_xor(hv[r], msk);

        // p = exp(score), fixed m=0 (scores bounded ~|Sigma|V||+|Vb| < 10)
        float p4[4];
        #pragma unroll
        for (int r = 0; r < 4; ++r)
            p4[r] = exp2f(fmaf(hv[r], LOG2E, vbl));

        l += (p4[0] + p4[1]) + (p4[2] + p4[3]);

        // p for local row = col: from lane group (col>>2), reg (col&3)
        int srcl = (col >> 2) * 16;
        float c0 = __shfl(p4[0], srcl);
        float c1 = __shfl(p4[1], srcl);
        float c2 = __shfl(p4[2], srcl);
        float c3 = __shfl(p4[3], srcl);
        float pa   = (col & 1) ? c1 : c0;
        float pb   = (col & 1) ? c3 : c2;
        float pcol = (col & 2) ? pb : pa;

        // PV: reuse the f32 tile regs; lane owns d = {grp*8+j, 32+grp*8+j}
        #pragma unroll
        for (int j = 0; j < 4; ++j) {
            acc16[j]      = fmaf(pcol, t.a00[j], acc16[j]);
            acc16[4 + j]  = fmaf(pcol, t.a01[j], acc16[4 + j]);
            acc16[8 + j]  = fmaf(pcol, t.a10[j], acc16[8 + j]);
            acc16[12 + j] = fmaf(pcol, t.a11[j], acc16[12 + j]);
        }
    };

    // ping-pong 2-deep pipeline (ntile is even); tile k at +k*4096 floats
    for (int it = 0; it < ntile; it += 2) {
        load_tile(B, xbase + (size_t)(it + 1) * 4096);
        compute(A);
        int nx = (it + 2 <= lastIt) ? (it + 2) : lastIt;   // last prefetch clamped (unused)
        load_tile(A, xbase + (size_t)nx * 4096);
        compute(B);
    }

    // ---------------- end reductions ----------------
    #pragma unroll
    for (int msk = 1; msk <= 8; msk <<= 1)
        #pragma unroll
        for (int i = 0; i < 16; ++i)
            acc16[i] += __shfl_xor(acc16[i], msk);

    l += __shfl_xor(l, 16);
    l += __shfl_xor(l, 32);

    if (col == 0) {
        #pragma unroll
        for (int j = 0; j < 8; ++j) {
            accbuf[wv][grp * 8 + j]      = acc16[j];
            accbuf[wv][32 + grp * 8 + j] = acc16[8 + j];
        }
    }
    if (lane == 0) lbuf[wv] = l;
    __syncthreads();

    if (tid < 64) {
        float a = (accbuf[0][tid] + accbuf[1][tid])
                + (accbuf[2][tid] + accbuf[3][tid]);
        accws[(size_t)blockIdx.x * 64 + tid] = a;
        if (tid == 0)
            lws[blockIdx.x] = (lbuf[0] + lbuf[1]) + (lbuf[2] + lbuf[3]);
    }
}

// ---------------- kernel 2: combine quarters ----------------
__global__ __launch_bounds__(64)
void attn_combine(const float* __restrict__ accws, const float* __restrict__ lws,
                  float* __restrict__ out)
{
    const int b = blockIdx.x, d = threadIdx.x;
    float a = (accws[(size_t)(4 * b) * 64 + d]     + accws[(size_t)(4 * b + 1) * 64 + d])
            + (accws[(size_t)(4 * b + 2) * 64 + d] + accws[(size_t)(4 * b + 3) * 64 + d]);
    float L = (lws[4 * b] + lws[4 * b + 1]) + (lws[4 * b + 2] + lws[4 * b + 3]);
    out[(size_t)b * 64 + d] = a / L;
}

extern "C" void kernel_launch(void* const* d_in, const int* in_sizes, int n_in,
                              void* d_out, int out_size, void* d_ws, size_t ws_size,
                              hipStream_t stream) {
    const float* full = (const float*)d_in[0];
    const float* last = (const float*)d_in[1];
    const float* W1w  = (const float*)d_in[2];
    const float* W1b  = (const float*)d_in[3];
    const float* W2w  = (const float*)d_in[4];
    const float* W2b  = (const float*)d_in[5];
    const float* Vw   = (const float*)d_in[6];
    const float* Vb   = (const float*)d_in[7];
    float* out = (float*)d_out;

    const int Bn = in_sizes[1] / 64;              // 1024
    const int T  = in_sizes[0] / in_sizes[1];     // 2048

    float* accws = (float*)d_ws;                  // [4*Bn][64]
    float* lws   = accws + (size_t)4 * Bn * 64;   // [4*Bn]

    attn_part<<<4 * Bn, 256, 0, stream>>>(full, last, W1w, W1b, W2w, W2b, Vw, Vb,
                                          accws, lws, T);
    attn_combine<<<Bn, 64, 0, stream>>>(accws, lws, out);
}

// Round 12
// 112.802 us; speedup vs baseline: 2.7947x; 1.0337x over previous
//
#include <hip/hip_runtime.h>
#include <hip/hip_bf16.h>

typedef __attribute__((ext_vector_type(8))) short bf16x8;
typedef __attribute__((ext_vector_type(4))) float f32x4;

#define LOG2E 1.4426950408889634f

__device__ __forceinline__ ushort f2bf(float f) {
    // RNE f32->bf16 via header cast; compiler fuses pairs into v_cvt_pk_bf16_f32
    return __builtin_bit_cast(ushort, __float2bfloat16(f));
}

struct TileRegs { f32x4 a00, a01, a10, a11; };

__device__ __forceinline__ void load_tile(TileRegs& t, const float* xr) {
    t.a00 = *reinterpret_cast<const f32x4*>(xr);
    t.a01 = *reinterpret_cast<const f32x4*>(xr + 4);
    t.a10 = *reinterpret_cast<const f32x4*>(xr + 32);
    t.a11 = *reinterpret_cast<const f32x4*>(xr + 36);
}

// ---------------- kernel 1: per-half-row partial (Sum p*x, Sum p) ----------------
__global__ __launch_bounds__(256, 4)
void attn_part(const float* __restrict__ full,
               const float* __restrict__ last,
               const float* __restrict__ W1w, const float* __restrict__ W1b,
               const float* __restrict__ W2w, const float* __restrict__ W2b,
               const float* __restrict__ Vw,  const float* __restrict__ Vb,
               float* __restrict__ accws, float* __restrict__ lws, int T)
{
    __shared__ ushort w2bf[64][64];     // bf16 bits of W2 [o][d]
    __shared__ float qpart[4][64];
    __shared__ float qt[64];            // q~ = W1b + W2b + last @ W1^T
    __shared__ float vsh[64];
    __shared__ float accbuf[4][64];
    __shared__ float lbuf[4];

    const int b    = blockIdx.x >> 1;   // batch row
    const int half = blockIdx.x & 1;    // which T-half
    const int tid  = threadIdx.x;
    const int lane = tid & 63;
    const int wv   = tid >> 6;          // wave 0..3
    const int col  = lane & 15;         // A-row (t) index / B,D col (o) index
    const int grp  = lane >> 4;         // k-group
    const int koff = grp * 8;

    // ---------------- stage 0: q~, W2->bf16, V ----------------
    {
        int o = tid & 63, pg = tid >> 6;
        const float4* lr = reinterpret_cast<const float4*>(last + (size_t)b * 64 + pg * 16);
        const float4* wr = reinterpret_cast<const float4*>(W1w + (size_t)o * 64 + pg * 16);
        float s = 0.f;
        #pragma unroll
        for (int j = 0; j < 4; ++j) {
            float4 a = lr[j], w = wr[j];
            s = fmaf(a.x, w.x, s); s = fmaf(a.y, w.y, s);
            s = fmaf(a.z, w.z, s); s = fmaf(a.w, w.w, s);
        }
        qpart[pg][o] = s;

        int base = tid * 16;
        #pragma unroll
        for (int j = 0; j < 16; j += 4) {
            float4 w4 = *reinterpret_cast<const float4*>(W2w + base + j);
            ushort* dst = &w2bf[0][0] + base + j;
            dst[0] = f2bf(w4.x); dst[1] = f2bf(w4.y);
            dst[2] = f2bf(w4.z); dst[3] = f2bf(w4.w);
        }
        if (tid < 64) vsh[tid] = Vw[tid];
    }
    __syncthreads();
    if (tid < 64)
        qt[tid] = W1b[tid] + W2b[tid] + qpart[0][tid] + qpart[1][tid]
                + qpart[2][tid] + qpart[3][tid];
    __syncthreads();

    // B fragments: B[k=d, c=o] = W2^T  -> lane holds W2[ot*16+col][kc*32+koff .. +7]
    bf16x8 bfr[4][2];
    #pragma unroll
    for (int ot = 0; ot < 4; ++ot)
        #pragma unroll
        for (int kc = 0; kc < 2; ++kc)
            bfr[ot][kc] = *reinterpret_cast<const bf16x8*>(
                              &w2bf[ot * 16 + col][kc * 32 + koff]);

    // per-col folded constants
    float q2[4], vm2[4], sv = 0.f;
    #pragma unroll
    for (int ot = 0; ot < 4; ++ot) {
        float v = vsh[ot * 16 + col];
        vm2[ot] = -2.f * v;
        sv += v;
        q2[ot] = qt[ot * 16 + col] * (2.f * LOG2E);
    }
    const float vbl = Vb[0] * LOG2E;

    const int ntile = T / (2 * 4 * 16); // tiles per wave (T=2048 -> 16)
    // waves interleave tiles of the block's contiguous 256KB half-row stream
    // (wave wv owns tiles wv, wv+4, ...); tile k at xbase + k*4096 floats
    const float* xbase = full + ((size_t)b * T + (size_t)half * (T / 2)
                                 + (size_t)wv * 16 + col) * 64 + koff;

    float acc16[16];
    #pragma unroll
    for (int i = 0; i < 16; ++i) acc16[i] = 0.f;
    float l = 0.f;

    const int lastIt = ntile - 1;

    TileRegs A, B;
    load_tile(A, xbase);

    // compute one 16-row tile held in regs `t`
    auto compute = [&](const TileRegs& t) {
        bf16x8 af0, af1;
        af0[0]=f2bf(t.a00[0]); af0[1]=f2bf(t.a00[1]); af0[2]=f2bf(t.a00[2]); af0[3]=f2bf(t.a00[3]);
        af0[4]=f2bf(t.a01[0]); af0[5]=f2bf(t.a01[1]); af0[6]=f2bf(t.a01[2]); af0[7]=f2bf(t.a01[3]);
        af1[0]=f2bf(t.a10[0]); af1[1]=f2bf(t.a10[1]); af1[2]=f2bf(t.a10[2]); af1[3]=f2bf(t.a10[3]);
        af1[4]=f2bf(t.a11[0]); af1[5]=f2bf(t.a11[1]); af1[6]=f2bf(t.a11[2]); af1[7]=f2bf(t.a11[3]);

        // hv[r] = sum_o V[o]*tanh(q_o + k[t,o]),  t-row = grp*4 + r (pre-reduction)
        float hv[4] = {sv, sv, sv, sv};
        #pragma unroll
        for (int ot = 0; ot < 4; ++ot) {
            f32x4 dd = {0.f, 0.f, 0.f, 0.f};
            dd = __builtin_amdgcn_mfma_f32_16x16x32_bf16(af0, bfr[ot][0], dd, 0, 0, 0);
            dd = __builtin_amdgcn_mfma_f32_16x16x32_bf16(af1, bfr[ot][1], dd, 0, 0, 0);
            #pragma unroll
            for (int r = 0; r < 4; ++r) {
                // tanh(x) = 1 - 2/(exp2(2x*log2e)+1); the "+1*v" is folded into sv
                float e  = exp2f(fmaf(dd[r], 2.f * LOG2E, q2[ot]));
                float rc = __builtin_amdgcn_rcpf(e + 1.f);
                hv[r] = fmaf(vm2[ot], rc, hv[r]);
            }
        }

        // reduce over the 16 o-cols (lane bits 0..3)
        #pragma unroll
        for (int msk = 1; msk <= 8; msk <<= 1)
            #pragma unroll
            for (int r = 0; r < 4; ++r)
                hv[r] += __shfl_xor(hv[r], msk);

        // p = exp(score), fixed m=0 (scores bounded ~|Sigma|V||+|Vb| < 10)
        float p4[4];
        #pragma unroll
        for (int r = 0; r < 4; ++r)
            p4[r] = exp2f(fmaf(hv[r], LOG2E, vbl));

        l += (p4[0] + p4[1]) + (p4[2] + p4[3]);

        // p for local row = col: from lane group (col>>2), reg (col&3)
        int srcl = (col >> 2) * 16;
        float c0 = __shfl(p4[0], srcl);
        float c1 = __shfl(p4[1], srcl);
        float c2 = __shfl(p4[2], srcl);
        float c3 = __shfl(p4[3], srcl);
        float pa   = (col & 1) ? c1 : c0;
        float pb   = (col & 1) ? c3 : c2;
        float pcol = (col & 2) ? pb : pa;

        // PV: reuse the f32 tile regs; lane owns d = {grp*8+j, 32+grp*8+j}
        #pragma unroll
        for (int j = 0; j < 4; ++j) {
            acc16[j]      = fmaf(pcol, t.a00[j], acc16[j]);
            acc16[4 + j]  = fmaf(pcol, t.a01[j], acc16[4 + j]);
            acc16[8 + j]  = fmaf(pcol, t.a10[j], acc16[8 + j]);
            acc16[12 + j] = fmaf(pcol, t.a11[j], acc16[12 + j]);
        }
    };

    // ping-pong 2-deep pipeline (ntile is even); tile k at +k*4096 floats
    for (int it = 0; it < ntile; it += 2) {
        load_tile(B, xbase + (size_t)(it + 1) * 4096);
        compute(A);
        int nx = (it + 2 <= lastIt) ? (it + 2) : lastIt;   // last prefetch clamped (unused)
        load_tile(A, xbase + (size_t)nx * 4096);
        compute(B);
    }

    // ---------------- end reductions ----------------
    #pragma unroll
    for (int msk = 1; msk <= 8; msk <<= 1)
        #pragma unroll
        for (int i = 0; i < 16; ++i)
            acc16[i] += __shfl_xor(acc16[i], msk);

    l += __shfl_xor(l, 16);
    l += __shfl_xor(l, 32);

    if (col == 0) {
        #pragma unroll
        for (int j = 0; j < 8; ++j) {
            accbuf[wv][grp * 8 + j]      = acc16[j];
            accbuf[wv][32 + grp * 8 + j] = acc16[8 + j];
        }
    }
    if (lane == 0) lbuf[wv] = l;
    __syncthreads();

    if (tid < 64) {
        float a = (accbuf[0][tid] + accbuf[1][tid])
                + (accbuf[2][tid] + accbuf[3][tid]);
        accws[(size_t)blockIdx.x * 64 + tid] = a;
        if (tid == 0)
            lws[blockIdx.x] = (lbuf[0] + lbuf[1]) + (lbuf[2] + lbuf[3]);
    }
}

// ---------------- kernel 2: combine halves ----------------
__global__ __launch_bounds__(64)
void attn_combine(const float* __restrict__ accws, const float* __restrict__ lws,
                  float* __restrict__ out)
{
    const int b = blockIdx.x, d = threadIdx.x;
    float a = accws[(size_t)(2 * b) * 64 + d] + accws[(size_t)(2 * b + 1) * 64 + d];
    float L = lws[2 * b] + lws[2 * b + 1];
    out[(size_t)b * 64 + d] = a / L;
}

extern "C" void kernel_launch(void* const* d_in, const int* in_sizes, int n_in,
                              void* d_out, int out_size, void* d_ws, size_t ws_size,
                              hipStream_t stream) {
    const float* full = (const float*)d_in[0];
    const float* last = (const float*)d_in[1];
    const float* W1w  = (const float*)d_in[2];
    const float* W1b  = (const float*)d_in[3];
    const float* W2w  = (const float*)d_in[4];
    const float* W2b  = (const float*)d_in[5];
    const float* Vw   = (const float*)d_in[6];
    const float* Vb   = (const float*)d_in[7];
    float* out = (float*)d_out;

    const int Bn = in_sizes[1] / 64;              // 1024
    const int T  = in_sizes[0] / in_sizes[1];     // 2048

    float* accws = (float*)d_ws;                  // [2*Bn][64]
    float* lws   = accws + (size_t)2 * Bn * 64;   // [2*Bn]

    attn_part<<<2 * Bn, 256, 0, stream>>>(full, last, W1w, W1b, W2w, W2b, Vw, Vb,
                                          accws, lws, T);
    attn_combine<<<Bn, 64, 0, stream>>>(accws, lws, out);
}